// Round 13
// baseline (532.685 us; speedup 1.0000x reference)
//
#include <hip/hip_runtime.h>
#include <hip/hip_bf16.h>
#include <math.h>

// Problem shape (fixed): B=8, L=2048, D=1024, n=16, d=64
#define BATCH 8
#define SEQL  2048
#define DIM   1024
#define MROWS (BATCH * SEQL)   // 16384

typedef _Float16 f16;
typedef _Float16 f16x8 __attribute__((ext_vector_type(8)));
typedef _Float16 f16x4 __attribute__((ext_vector_type(4)));
typedef _Float16 f16x2 __attribute__((ext_vector_type(2)));
typedef float f32x4 __attribute__((ext_vector_type(4)));

typedef const __attribute__((address_space(1))) void* gp_t;
typedef __attribute__((address_space(3))) void* lp_t;
#define GLL(src, dst) __builtin_amdgcn_global_load_lds((gp_t)(src), (lp_t)(dst), 16, 0, 0)

// ---------------------------------------------------------------------------
__global__ __launch_bounds__(64) void zero_flags(int* f) { f[threadIdx.x] = 0; }

// merged fp32->f16 converts: x -> xh, Wk|Wkg -> Wcat, Wout -> Wouth. One dispatch.
__global__ __launch_bounds__(256) void cvt_all(const float* __restrict__ x,
                                               const float* __restrict__ Wk,
                                               const float* __restrict__ Wkg,
                                               const float* __restrict__ Wout,
                                               f16* __restrict__ xh,
                                               f16* __restrict__ Wcat,
                                               f16* __restrict__ Wouth)
{
    int i = blockIdx.x * 256 + threadIdx.x;          // 8-elem groups
    const float* src; f16* dst;
    if (i < 2097152)      { src = x;    dst = xh;             }
    else if (i < 2228224) { src = Wk;   dst = Wcat;           i -= 2097152; }
    else if (i < 2359296) { src = Wkg;  dst = Wcat + 1048576; i -= 2228224; }
    else                  { src = Wout; dst = Wouth;          i -= 2359296; }
    const float4* p = (const float4*)src + (size_t)i * 2;
    const float4 a = p[0], b = p[1];
    f16x8 v;
    v[0] = (f16)a.x; v[1] = (f16)a.y; v[2] = (f16)a.z; v[3] = (f16)a.w;
    v[4] = (f16)b.x; v[5] = (f16)b.y; v[6] = (f16)b.z; v[7] = (f16)b.w;
    *(f16x8*)(dst + (size_t)i * 8) = v;
}

// ---------------------------------------------------------------------------
// 256x256-tile 8-phase f16 MFMA GEMM tile (R8/R11-proven body), device fn
// with runtime bm/bn and passed LDS (128 KiB).
// MODE 0: fp32 C0, N=1024.  MODE 1: N=2048 split: col<1024 -> f16 k (C0),
// col>=1024 -> sigmoid(+bias) f16 g (C1).
template<int MODE>
__device__ __forceinline__ void gemm_tile(const f16* __restrict__ A,
                                          const f16* __restrict__ Bw,
                                          const float* __restrict__ bias,
                                          void* __restrict__ C0,
                                          void* __restrict__ C1,
                                          int bm, int bn, f16* lds)
{
    constexpr int K   = 1024;
    constexpr int NKT = 16;             // K/64

    const int tid = threadIdx.x;
    const int w = tid >> 6, l = tid & 63;
    const int wm = w >> 2, wn = w & 3;
    const int lrow = l & 15;
    const int l7 = l & 7, lk = l >> 4;

    const int srl   = tid >> 3;
    const int sg    = tid & 7;
    const int scolx = (sg ^ (srl & 7)) * 8;     // inverse-swizzled source col

    const int g0 = ((lk) ^ l7) * 8;
    const int g1 = ((4 + lk) ^ l7) * 8;

#define STAGE(t, m, P, rowbase, h)                                                       \
    do {                                                                                 \
        const int _rf0 = (h) * 128 + srl;                                                \
        GLL((P) + (size_t)((rowbase) + _rf0) * K + (t) * 64 + scolx,                     \
            lds + (((t) & 1) * 2 + (m)) * 16384 + _rf0 * 64 + sg * 8);                   \
        const int _rf1 = _rf0 + 64;                                                      \
        GLL((P) + (size_t)((rowbase) + _rf1) * K + (t) * 64 + scolx,                     \
            lds + (((t) & 1) * 2 + (m)) * 16384 + _rf1 * 64 + sg * 8);                   \
    } while (0)

    f32x4 acc[8][4];
    #pragma unroll
    for (int mi = 0; mi < 8; ++mi)
        #pragma unroll
        for (int ni = 0; ni < 4; ++ni) acc[mi][ni] = (f32x4){0.f, 0.f, 0.f, 0.f};

    f16x8 bf[4][2];

#define PHASE(p, cur, STG, LOAD_B)                                                       \
    do {                                                                                 \
        const f16* _ab = lds + (cur) * 32768;                                            \
        const int _ar = (wm * 128 + (2 * (p)) * 16 + lrow) * 64;                         \
        f16x8 a00 = *(const f16x8*)(_ab + _ar + g0);                                     \
        f16x8 a01 = *(const f16x8*)(_ab + _ar + g1);                                     \
        f16x8 a10 = *(const f16x8*)(_ab + _ar + 1024 + g0);                              \
        f16x8 a11 = *(const f16x8*)(_ab + _ar + 1024 + g1);                              \
        if (LOAD_B) {                                                                    \
            const f16* _bb = _ab + 16384;                                                \
            _Pragma("unroll")                                                            \
            for (int ni = 0; ni < 4; ++ni) {                                             \
                const int _br = (wn * 64 + ni * 16 + lrow) * 64;                         \
                bf[ni][0] = *(const f16x8*)(_bb + _br + g0);                             \
                bf[ni][1] = *(const f16x8*)(_bb + _br + g1);                             \
            }                                                                            \
        }                                                                                \
        STG;                                                                             \
        __builtin_amdgcn_s_barrier();                                                    \
        asm volatile("s_waitcnt lgkmcnt(0)" ::: "memory");                               \
        __builtin_amdgcn_sched_barrier(0);                                               \
        __builtin_amdgcn_s_setprio(1);                                                   \
        _Pragma("unroll")                                                                \
        for (int ni = 0; ni < 4; ++ni) {                                                 \
            acc[2*(p)][ni]   = __builtin_amdgcn_mfma_f32_16x16x32_f16(a00, bf[ni][0], acc[2*(p)][ni], 0, 0, 0);   \
            acc[2*(p)][ni]   = __builtin_amdgcn_mfma_f32_16x16x32_f16(a01, bf[ni][1], acc[2*(p)][ni], 0, 0, 0);   \
            acc[2*(p)+1][ni] = __builtin_amdgcn_mfma_f32_16x16x32_f16(a10, bf[ni][0], acc[2*(p)+1][ni], 0, 0, 0); \
            acc[2*(p)+1][ni] = __builtin_amdgcn_mfma_f32_16x16x32_f16(a11, bf[ni][1], acc[2*(p)+1][ni], 0, 0, 0); \
        }                                                                                \
        __builtin_amdgcn_s_setprio(0);                                                   \
    } while (0)

    // prologue: A(0),B(0),B(1); wait A(0)+B(0)
    STAGE(0, 0, A, bm, 0);  STAGE(0, 0, A, bm, 1);
    STAGE(0, 1, Bw, bn, 0); STAGE(0, 1, Bw, bn, 1);
    STAGE(1, 1, Bw, bn, 0); STAGE(1, 1, Bw, bn, 1);
    asm volatile("s_waitcnt vmcnt(4)" ::: "memory");
    __builtin_amdgcn_s_barrier();

    for (int t = 0; t < NKT; ++t) {
        const int cur = t & 1;
        PHASE(0, cur, { if (t + 1 < NKT) STAGE(t + 1, 0, A, bm, 0); }, 1);
        __builtin_amdgcn_s_barrier();
        PHASE(1, cur, { if (t + 1 < NKT) STAGE(t + 1, 0, A, bm, 1); }, 0);
        __builtin_amdgcn_s_barrier();
        PHASE(2, cur, { if (t + 2 < NKT) STAGE(t + 2, 1, Bw, bn, 0); }, 0);
        __builtin_amdgcn_s_barrier();
        PHASE(3, cur, { if (t + 2 < NKT) STAGE(t + 2, 1, Bw, bn, 1); }, 0);
        if (t + 2 < NKT)      asm volatile("s_waitcnt vmcnt(4)" ::: "memory");
        else if (t + 1 < NKT) asm volatile("s_waitcnt vmcnt(0)" ::: "memory");
        __builtin_amdgcn_s_barrier();
    }
#undef PHASE
#undef STAGE

    const int orow = (l >> 4) * 4;
    const int ocol = l & 15;
    #pragma unroll
    for (int mi = 0; mi < 8; ++mi) {
        #pragma unroll
        for (int ni = 0; ni < 4; ++ni) {
            const int col  = bn + wn * 64 + ni * 16 + ocol;
            const int row0 = bm + wm * 128 + mi * 16 + orow;
            #pragma unroll
            for (int r = 0; r < 4; ++r) {
                float v = acc[mi][ni][r];
                if (MODE == 0) {
                    ((float*)C0)[(size_t)(row0 + r) * DIM + col] = v;
                } else {
                    if (col < DIM) {
                        ((f16*)C0)[(size_t)(row0 + r) * DIM + col] = (f16)v;     // k
                    } else {
                        v += bias[col - DIM];
                        v = 1.f / (1.f + __expf(-v));                            // g
                        ((f16*)C1)[(size_t)(row0 + r) * DIM + (col - DIM)] = (f16)v;
                    }
                }
            }
        }
    }
}

// standalone out-GEMM (proven R8/R12 config, XCD-swizzled grid of 256)
__global__ __launch_bounds__(512, 2) void gemm_out(const f16* __restrict__ A,
                                                   const f16* __restrict__ Bw,
                                                   float* __restrict__ C)
{
    __shared__ f16 lds[4 * 16384];   // 128 KiB
    const int cpx = gridDim.x >> 3;
    const int lt  = (blockIdx.x & 7) * cpx + (blockIdx.x >> 3);
    const int bm  = (lt >> 2) * 256;
    const int bn  = (lt & 3) * 256;
    gemm_tile<0>(A, Bw, nullptr, C, nullptr, bm, bn, lds);
}

// ---------------------------------------------------------------------------
// DPP cross-lane add (VALU latency). CTRL compile-time.
template<int CTRL>
__device__ __forceinline__ float dpp_add_f(float s) {
    int t = __builtin_amdgcn_update_dpp(0, __float_as_int(s), CTRL, 0xF, 0xF, true);
    return s + __int_as_float(t);
}

__device__ __forceinline__ float sumsq4(f16x2 a, f16x2 b) {
    return __builtin_amdgcn_fdot2(a, a, __builtin_amdgcn_fdot2(b, b, 0.f, false), false);
}

#define PF 16   // scan prefetch depth (divides 256)

// ---------------------------------------------------------------------------
// Fused kg-GEMM + scan (NO out-phase fusion; out is a separate dispatch):
//   blocks 0..223  : kg workers. xcd/batch b = bid&7, j = bid>>3 (0..27).
//                    Tiles c-major (s = j+28r; c=s>>3, n=s&7) -> chunks c=0..2
//                    of every batch complete in the first worker round.
//   blocks 224..255: scan, 1 wave (R7-proven step: 16-lane/4-hop/4-dim,
//                    packed f16, PF=16 ring). batch b = bid&7, quad q.
// Sync: kgf[b*8+c] counts kg tiles (to 8); workers release with
// __syncthreads+threadfence+atomicAdd; scan polls RELAXED (+s_sleep), then
// ONE __threadfence per chunk. (R11 lesson: acquire-per-poll invalidates the
// polling XCD's caches -> 4x slowdown. Relaxed polls don't.)
// Batch pinned to XCD: kg writes and scan reads of batch b share one L2.
// Scan writes o into xh: rows of panel (b,c) are only read by that panel's
// 8 kg tiles, all complete before the scan touches them.
__global__ __launch_bounds__(512, 2) void mega(const f16* __restrict__ xh,
                                               const f16* __restrict__ Wcat,
                                               const float* __restrict__ bkg,
                                               f16* __restrict__ Kh,
                                               f16* __restrict__ Gh,
                                               f16* __restrict__ Ov,     // = xh
                                               int* __restrict__ kgf)
{
    __shared__ f16 lds[4 * 16384];   // 128 KiB

    const int bid = blockIdx.x;
    if (bid < 224) {
        // ---------------- kg worker ----------------
        const int b = bid & 7;          // XCD == batch
        const int j = bid >> 3;         // 0..27
        for (int r = 0; r < 3; ++r) {
            const int s = j + 28 * r;
            if (s >= 64) break;
            const int c = s >> 3, n = s & 7;
            gemm_tile<1>(xh, Wcat, bkg, Kh, Gh, b * 2048 + c * 256, n * 256, lds);
            __syncthreads();            // all waves' stores drained (vmcnt 0)
            if (threadIdx.x == 0) {
                __threadfence();
                atomicAdd(&kgf[b * 8 + c], 1);   // device-scope by default
            }
        }
    } else {
        // ---------------- scan (1 wave) ----------------
        if (threadIdx.x >= 64) return;
        const int b = bid & 7;
        const int q = (bid - 224) >> 3;       // head-quad 0..3
        const int l = threadIdx.x;

        const size_t base = (size_t)b * (SEQL * DIM) + (size_t)(q * 256 + l * 4);
        f16x2 h01 = (f16x2){(f16)0.f, (f16)0.f};
        f16x2 h23 = (f16x2){(f16)0.f, (f16)0.f};

        #define SCAN_STEP(kc, gc)                                                      \
            do {                                                                       \
                const f16x2 k01 = __builtin_shufflevector((kc), (kc), 0, 1);           \
                const f16x2 k23 = __builtin_shufflevector((kc), (kc), 2, 3);           \
                const f16x2 g01 = __builtin_shufflevector((gc), (gc), 0, 1);           \
                const f16x2 g23 = __builtin_shufflevector((gc), (gc), 2, 3);           \
                const f16x2 u01 = h01 * g01;                                           \
                const f16x2 u23 = h23 * g23;                                           \
                float s = sumsq4(h01, h23);                                            \
                s = dpp_add_f<0xB1>(s);                                                \
                s = dpp_add_f<0x4E>(s);                                                \
                s = dpp_add_f<0x141>(s);                                               \
                s = dpp_add_f<0x140>(s);                                               \
                const float inv = __builtin_amdgcn_rsqf(fmaf(s, 0.015625f, 1e-8f));    \
                const f16 ih = (f16)inv;                                               \
                const f16x2 iv = (f16x2){ih, ih};                                      \
                h01 = u01 * iv + k01;                                                  \
                h23 = u23 * iv + k23;                                                  \
                f16x4 o;                                                               \
                o[0] = h01[0]; o[1] = h01[1]; o[2] = h23[0]; o[3] = h23[1];            \
                *(f16x4*)(Ov + off) = o;                                               \
                off += DIM;                                                            \
            } while (0)

        for (int c = 0; c < 8; ++c) {
            // relaxed poll; single fence once ready (no acquire-per-poll!)
            while (__hip_atomic_load(&kgf[b * 8 + c],
                                     __ATOMIC_RELAXED, __HIP_MEMORY_SCOPE_AGENT) < 8)
                __builtin_amdgcn_s_sleep(8);
            __threadfence();

            size_t off = base + (size_t)(c * 256) * DIM;
            f16x4 kb[PF], gb[PF];
            #pragma unroll
            for (int u = 0; u < PF; ++u) {
                kb[u] = *(const f16x4*)(Kh + off + (size_t)u * DIM);
                gb[u] = *(const f16x4*)(Gh + off + (size_t)u * DIM);
            }
            for (int t0 = 0; t0 + PF < 256; t0 += PF) {
                #pragma unroll
                for (int u = 0; u < PF; ++u) {
                    const f16x4 kc = kb[u], gc = gb[u];
                    const size_t poff = off + (size_t)PF * DIM;   // stays in chunk
                    kb[u] = *(const f16x4*)(Kh + poff);
                    gb[u] = *(const f16x4*)(Gh + poff);
                    SCAN_STEP(kc, gc);
                }
            }
            #pragma unroll
            for (int u = 0; u < PF; ++u) {
                const f16x4 kc = kb[u], gc = gb[u];
                SCAN_STEP(kc, gc);
            }
        }
        #undef SCAN_STEP
    }
}

// ---------------------------------------------------------------------------
extern "C" void kernel_launch(void* const* d_in, const int* in_sizes, int n_in,
                              void* d_out, int out_size, void* d_ws, size_t ws_size,
                              hipStream_t stream) {
    const float* x    = (const float*)d_in[0];
    const float* Wk   = (const float*)d_in[1];
    const float* Wkg  = (const float*)d_in[2];
    const float* bkg  = (const float*)d_in[3];
    const float* Wout = (const float*)d_in[4];
    float* out = (float*)d_out;

    // workspace (f16): xh/Kh/Gh 32MB each + Wcat 4MB + Wouth 2MB + flags
    f16* xh    = (f16*)d_ws;                         // [M, D]; scan output reuses it
    f16* Kh    = xh    + (size_t)MROWS * DIM;
    f16* Gh    = Kh    + (size_t)MROWS * DIM;
    f16* Wcat  = Gh    + (size_t)MROWS * DIM;        // [2048, 1024]: Wk ; Wkg
    f16* Wouth = Wcat  + (size_t)2 * DIM * DIM;
    int* flags = (int*)(Wouth + (size_t)DIM * DIM);  // 64 ints

    zero_flags<<<dim3(1), dim3(64), 0, stream>>>(flags);

    // merged converts: one dispatch (x + Wk + Wkg + Wout)
    cvt_all<<<dim3(9728), dim3(256), 0, stream>>>(x, Wk, Wkg, Wout, xh, Wcat, Wouth);

    // fused kg-GEMM + scan (o -> xh), flag-gated, batch-per-XCD
    mega<<<dim3(256), dim3(512), 0, stream>>>(xh, Wcat, bkg, Kh, Gh, xh, flags);

    // out = o @ Wout.T (separate dispatch, no polling): 64 x 4 = 256 blocks
    gemm_out<<<dim3(256), dim3(512), 0, stream>>>(xh, Wouth, out);
}

// Round 14
// 288.661 us; speedup vs baseline: 1.8454x; 1.8454x over previous
//
#include <hip/hip_runtime.h>
#include <hip/hip_bf16.h>
#include <math.h>

// Problem shape (fixed): B=8, L=2048, D=1024, n=16, d=64
#define BATCH 8
#define SEQL  2048
#define DIM   1024
#define MROWS (BATCH * SEQL)   // 16384

typedef _Float16 f16;
typedef _Float16 f16x8 __attribute__((ext_vector_type(8)));
typedef _Float16 f16x4 __attribute__((ext_vector_type(4)));
typedef _Float16 f16x2 __attribute__((ext_vector_type(2)));
typedef float f32x4 __attribute__((ext_vector_type(4)));

typedef const __attribute__((address_space(1))) void* gp_t;
typedef __attribute__((address_space(3))) void* lp_t;
#define GLL(src, dst) __builtin_amdgcn_global_load_lds((gp_t)(src), (lp_t)(dst), 16, 0, 0)

// ---------------------------------------------------------------------------
// merged fp32->f16 converts: x -> xh, Wk|Wkg -> Wcat, Wout -> Wouth. One dispatch.
__global__ __launch_bounds__(256) void cvt_all(const float* __restrict__ x,
                                               const float* __restrict__ Wk,
                                               const float* __restrict__ Wkg,
                                               const float* __restrict__ Wout,
                                               f16* __restrict__ xh,
                                               f16* __restrict__ Wcat,
                                               f16* __restrict__ Wouth)
{
    int i = blockIdx.x * 256 + threadIdx.x;          // 8-elem groups
    const float* src; f16* dst;
    if (i < 2097152)      { src = x;    dst = xh;             }
    else if (i < 2228224) { src = Wk;   dst = Wcat;           i -= 2097152; }
    else if (i < 2359296) { src = Wkg;  dst = Wcat + 1048576; i -= 2228224; }
    else                  { src = Wout; dst = Wouth;          i -= 2359296; }
    const float4* p = (const float4*)src + (size_t)i * 2;
    const float4 a = p[0], b = p[1];
    f16x8 v;
    v[0] = (f16)a.x; v[1] = (f16)a.y; v[2] = (f16)a.z; v[3] = (f16)a.w;
    v[4] = (f16)b.x; v[5] = (f16)b.y; v[6] = (f16)b.z; v[7] = (f16)b.w;
    *(f16x8*)(dst + (size_t)i * 8) = v;
}

// ---------------------------------------------------------------------------
// 256x256-tile 8-phase f16 MFMA GEMM (T3+T4 counted vmcnt, T2 swizzle via
// inverse-swizzled global source, T5 setprio). R8-proven (294us config).
// MODE 0: fp32 C0, N=1024.  MODE 1: N=2048 split: col<1024 -> f16 k (C0),
// col>=1024 -> sigmoid(+bias) f16 g (C1).
template<int MODE>
__global__ __launch_bounds__(512, 2) void gemm8(const f16* __restrict__ A,
                                                const f16* __restrict__ Bw,
                                                const float* __restrict__ bias,
                                                void* __restrict__ C0,
                                                void* __restrict__ C1)
{
    constexpr int K   = 1024;
    constexpr int NTI = MODE ? 8 : 4;   // N/256
    constexpr int NKT = 16;             // K/64
    __shared__ f16 lds[2][2][256 * 64]; // [buf][A=0/B=1], 128 KiB

    const int tid = threadIdx.x;
    const int w = tid >> 6, l = tid & 63;
    const int wm = w >> 2, wn = w & 3;
    const int lrow = l & 15;
    const int l7 = l & 7, lk = l >> 4;

    // bijective XCD swizzle (grid % 8 == 0)
    const int cpx = gridDim.x >> 3;
    const int lt  = (blockIdx.x & 7) * cpx + (blockIdx.x >> 3);
    const int bm  = (lt / NTI) * 256;
    const int bn  = (lt % NTI) * 256;

    // staging geometry: 512 threads x 2 x 16B = one 128x64 half-tile
    const int srl   = tid >> 3;                 // 0..63 row within 64-row round
    const int sg    = tid & 7;                  // LDS granule slot
    const int scolx = (sg ^ (srl & 7)) * 8;     // inverse-swizzled source col

    // swizzled ds-read granule offsets (elems) for ks=0/1
    const int g0 = ((lk) ^ l7) * 8;
    const int g1 = ((4 + lk) ^ l7) * 8;

#define STAGE(t, m, P, rowbase, h)                                                       \
    do {                                                                                 \
        const int _rf0 = (h) * 128 + srl;                                                \
        GLL((P) + (size_t)((rowbase) + _rf0) * K + (t) * 64 + scolx,                     \
            &lds[(t) & 1][m][_rf0 * 64 + sg * 8]);                                       \
        const int _rf1 = _rf0 + 64;                                                      \
        GLL((P) + (size_t)((rowbase) + _rf1) * K + (t) * 64 + scolx,                     \
            &lds[(t) & 1][m][_rf1 * 64 + sg * 8]);                                       \
    } while (0)

    f32x4 acc[8][4];
    #pragma unroll
    for (int mi = 0; mi < 8; ++mi)
        #pragma unroll
        for (int ni = 0; ni < 4; ++ni) acc[mi][ni] = (f32x4){0.f, 0.f, 0.f, 0.f};

    f16x8 bf[4][2];

#define PHASE(p, cur, STG, LOAD_B)                                                       \
    do {                                                                                 \
        const f16* _ab = &lds[cur][0][0];                                                \
        const int _ar = (wm * 128 + (2 * (p)) * 16 + lrow) * 64;                         \
        f16x8 a00 = *(const f16x8*)(_ab + _ar + g0);                                     \
        f16x8 a01 = *(const f16x8*)(_ab + _ar + g1);                                     \
        f16x8 a10 = *(const f16x8*)(_ab + _ar + 1024 + g0);                              \
        f16x8 a11 = *(const f16x8*)(_ab + _ar + 1024 + g1);                              \
        if (LOAD_B) {                                                                    \
            const f16* _bb = &lds[cur][1][0];                                            \
            _Pragma("unroll")                                                            \
            for (int ni = 0; ni < 4; ++ni) {                                             \
                const int _br = (wn * 64 + ni * 16 + lrow) * 64;                         \
                bf[ni][0] = *(const f16x8*)(_bb + _br + g0);                             \
                bf[ni][1] = *(const f16x8*)(_bb + _br + g1);                             \
            }                                                                            \
        }                                                                                \
        STG;                                                                             \
        __builtin_amdgcn_s_barrier();                                                    \
        asm volatile("s_waitcnt lgkmcnt(0)" ::: "memory");                               \
        __builtin_amdgcn_sched_barrier(0);                                               \
        __builtin_amdgcn_s_setprio(1);                                                   \
        _Pragma("unroll")                                                                \
        for (int ni = 0; ni < 4; ++ni) {                                                 \
            acc[2*(p)][ni]   = __builtin_amdgcn_mfma_f32_16x16x32_f16(a00, bf[ni][0], acc[2*(p)][ni], 0, 0, 0);   \
            acc[2*(p)][ni]   = __builtin_amdgcn_mfma_f32_16x16x32_f16(a01, bf[ni][1], acc[2*(p)][ni], 0, 0, 0);   \
            acc[2*(p)+1][ni] = __builtin_amdgcn_mfma_f32_16x16x32_f16(a10, bf[ni][0], acc[2*(p)+1][ni], 0, 0, 0); \
            acc[2*(p)+1][ni] = __builtin_amdgcn_mfma_f32_16x16x32_f16(a11, bf[ni][1], acc[2*(p)+1][ni], 0, 0, 0); \
        }                                                                                \
        __builtin_amdgcn_s_setprio(0);                                                   \
    } while (0)

    // prologue: A(0),B(0),B(1); wait A(0)+B(0) (first 8 of 12 loads)
    STAGE(0, 0, A, bm, 0);  STAGE(0, 0, A, bm, 1);
    STAGE(0, 1, Bw, bn, 0); STAGE(0, 1, Bw, bn, 1);
    STAGE(1, 1, Bw, bn, 0); STAGE(1, 1, Bw, bn, 1);
    asm volatile("s_waitcnt vmcnt(4)" ::: "memory");
    __builtin_amdgcn_s_barrier();

    for (int t = 0; t < NKT; ++t) {
        const int cur = t & 1;
        PHASE(0, cur, { if (t + 1 < NKT) STAGE(t + 1, 0, A, bm, 0); }, 1);
        __builtin_amdgcn_s_barrier();
        PHASE(1, cur, { if (t + 1 < NKT) STAGE(t + 1, 0, A, bm, 1); }, 0);
        __builtin_amdgcn_s_barrier();
        PHASE(2, cur, { if (t + 2 < NKT) STAGE(t + 2, 1, Bw, bn, 0); }, 0);
        __builtin_amdgcn_s_barrier();
        PHASE(3, cur, { if (t + 2 < NKT) STAGE(t + 2, 1, Bw, bn, 1); }, 0);
        if (t + 2 < NKT)      asm volatile("s_waitcnt vmcnt(4)" ::: "memory");
        else if (t + 1 < NKT) asm volatile("s_waitcnt vmcnt(0)" ::: "memory");
        __builtin_amdgcn_s_barrier();
    }
#undef PHASE
#undef STAGE

    // epilogue: C/D layout col = l&15, row = (l>>4)*4 + r
    const int orow = (l >> 4) * 4;
    const int ocol = l & 15;
    #pragma unroll
    for (int mi = 0; mi < 8; ++mi) {
        #pragma unroll
        for (int ni = 0; ni < 4; ++ni) {
            const int col  = bn + wn * 64 + ni * 16 + ocol;
            const int row0 = bm + wm * 128 + mi * 16 + orow;
            #pragma unroll
            for (int r = 0; r < 4; ++r) {
                float v = acc[mi][ni][r];
                if (MODE == 0) {
                    ((float*)C0)[(size_t)(row0 + r) * DIM + col] = v;
                } else {
                    if (col < DIM) {
                        ((f16*)C0)[(size_t)(row0 + r) * DIM + col] = (f16)v;     // k
                    } else {
                        v += bias[col - DIM];
                        v = 1.f / (1.f + __expf(-v));                            // g
                        ((f16*)C1)[(size_t)(row0 + r) * DIM + (col - DIM)] = (f16)v;
                    }
                }
            }
        }
    }
}

// ---------------------------------------------------------------------------
// DPP cross-lane add (VALU latency). CTRL compile-time.
template<int CTRL>
__device__ __forceinline__ float dpp_add_f(float s) {
    int t = __builtin_amdgcn_update_dpp(0, __float_as_int(s), CTRL, 0xF, 0xF, true);
    return s + __int_as_float(t);
}

__device__ __forceinline__ float sumsq4(f16x2 a, f16x2 b) {
    return __builtin_amdgcn_fdot2(a, a, __builtin_amdgcn_fdot2(b, b, 0.f, false), false);
}

#define PF 16   // prefetch depth (steps); divides SEQL

// Scan (R7/R8-proven empirical optimum of this family: 128.6us standalone).
// 32 waves, 4 sequences/wave (16-lane rows), 4 dims/lane (f16x4), packed-f16
// state; 4-hop row-local DPP butterfly; inv = rsq(S/64 + 1e-8); PF=16 ring.
__global__ __launch_bounds__(64) void scan_kernel(const f16* __restrict__ Kv,
                                                  const f16* __restrict__ Gv,
                                                  f16* __restrict__ Ov)
{
    const int w = blockIdx.x;     // 0..31
    const int l = threadIdx.x;

    const size_t base = (size_t)(w >> 2) * (SEQL * DIM) + (size_t)((w & 3) * 256 + l * 4);
    f16x2 h01 = (f16x2){(f16)0.f, (f16)0.f};
    f16x2 h23 = (f16x2){(f16)0.f, (f16)0.f};

    f16x4 kb[PF], gb[PF];
    #pragma unroll
    for (int u = 0; u < PF; ++u) {
        kb[u] = *(const f16x4*)(Kv + base + (size_t)u * DIM);
        gb[u] = *(const f16x4*)(Gv + base + (size_t)u * DIM);
    }

    size_t off = base;

    #define SCAN_STEP(kc, gc)                                                          \
        do {                                                                           \
            const f16x2 k01 = __builtin_shufflevector((kc), (kc), 0, 1);               \
            const f16x2 k23 = __builtin_shufflevector((kc), (kc), 2, 3);               \
            const f16x2 g01 = __builtin_shufflevector((gc), (gc), 0, 1);               \
            const f16x2 g23 = __builtin_shufflevector((gc), (gc), 2, 3);               \
            const f16x2 u01 = h01 * g01;   /* v_pk_mul_f16 */                          \
            const f16x2 u23 = h23 * g23;                                               \
            float s = sumsq4(h01, h23);                                                \
            s = dpp_add_f<0xB1>(s);   /* xor1: quad_perm [1,0,3,2] */                  \
            s = dpp_add_f<0x4E>(s);   /* xor2: quad_perm [2,3,0,1] */                  \
            s = dpp_add_f<0x141>(s);  /* xor4: row_half_mirror */                      \
            s = dpp_add_f<0x140>(s);  /* xor8: row_mirror */                           \
            const float inv = __builtin_amdgcn_rsqf(fmaf(s, 0.015625f, 1e-8f));        \
            const f16 ih = (f16)inv;                                                   \
            const f16x2 iv = (f16x2){ih, ih};                                          \
            h01 = u01 * iv + k01;          /* v_pk_fma_f16 */                          \
            h23 = u23 * iv + k23;                                                      \
            f16x4 o;                                                                   \
            o[0] = h01[0]; o[1] = h01[1]; o[2] = h23[0]; o[3] = h23[1];                \
            *(f16x4*)(Ov + off) = o;                                                   \
            off += DIM;                                                                \
        } while (0)

    for (int t0 = 0; t0 + PF < SEQL; t0 += PF) {
        #pragma unroll
        for (int u = 0; u < PF; ++u) {
            const f16x4 kc = kb[u], gc = gb[u];
            const size_t poff = off + (size_t)PF * DIM;   // refill PF ahead
            kb[u] = *(const f16x4*)(Kv + poff);
            gb[u] = *(const f16x4*)(Gv + poff);
            SCAN_STEP(kc, gc);
        }
    }
    #pragma unroll
    for (int u = 0; u < PF; ++u) {
        const f16x4 kc = kb[u], gc = gb[u];
        SCAN_STEP(kc, gc);
    }
    #undef SCAN_STEP
}

// ---------------------------------------------------------------------------
extern "C" void kernel_launch(void* const* d_in, const int* in_sizes, int n_in,
                              void* d_out, int out_size, void* d_ws, size_t ws_size,
                              hipStream_t stream) {
    const float* x    = (const float*)d_in[0];
    const float* Wk   = (const float*)d_in[1];
    const float* Wkg  = (const float*)d_in[2];
    const float* bkg  = (const float*)d_in[3];
    const float* Wout = (const float*)d_in[4];
    float* out = (float*)d_out;

    // workspace (f16): xh/Kh/Gh 32MB each + Wcat 4MB + Wouth 2MB = 102MB
    f16* xh    = (f16*)d_ws;                         // [M, D]; scan output reuses it
    f16* Kh    = xh    + (size_t)MROWS * DIM;
    f16* Gh    = Kh    + (size_t)MROWS * DIM;
    f16* Wcat  = Gh    + (size_t)MROWS * DIM;        // [2048, 1024]: Wk ; Wkg
    f16* Wouth = Wcat  + (size_t)2 * DIM * DIM;

    // merged converts: one dispatch (x + Wk + Wkg + Wout), 9728 blocks
    cvt_all<<<dim3(9728), dim3(256), 0, stream>>>(x, Wk, Wkg, Wout, xh, Wcat, Wouth);

    // fused k|g GEMM: M=16384, N=2048 -> 64 x 8 = 512 blocks
    gemm8<1><<<dim3(512), dim3(512), 0, stream>>>(xh, Wcat, bkg, Kh, Gh);
    // scan: o -> xh (32 waves, 4 seqs each)
    scan_kernel<<<dim3(32), dim3(64), 0, stream>>>(Kh, Gh, xh);
    // out = o @ Wout.T: 64 x 4 = 256 blocks
    gemm8<0><<<dim3(256), dim3(512), 0, stream>>>(xh, Wouth, nullptr, out, nullptr);
}

// Round 15
// 189.178 us; speedup vs baseline: 2.8158x; 1.5259x over previous
//
#include <hip/hip_runtime.h>
#include <hip/hip_bf16.h>
#include <math.h>

// Problem shape (fixed): B=8, L=2048, D=1024, n=16, d=64
#define BATCH 8
#define SEQL  2048
#define DIM   1024
#define MROWS (BATCH * SEQL)   // 16384

typedef _Float16 f16;
typedef _Float16 f16x8 __attribute__((ext_vector_type(8)));
typedef _Float16 f16x4 __attribute__((ext_vector_type(4)));
typedef _Float16 f16x2 __attribute__((ext_vector_type(2)));
typedef float f32x4 __attribute__((ext_vector_type(4)));

typedef const __attribute__((address_space(1))) void* gp_t;
typedef __attribute__((address_space(3))) void* lp_t;
#define GLL(src, dst) __builtin_amdgcn_global_load_lds((gp_t)(src), (lp_t)(dst), 16, 0, 0)

// ---------------------------------------------------------------------------
// merged fp32->f16 converts: x -> xh, Wk|Wkg -> Wcat, Wout -> Wouth. One dispatch.
__global__ __launch_bounds__(256) void cvt_all(const float* __restrict__ x,
                                               const float* __restrict__ Wk,
                                               const float* __restrict__ Wkg,
                                               const float* __restrict__ Wout,
                                               f16* __restrict__ xh,
                                               f16* __restrict__ Wcat,
                                               f16* __restrict__ Wouth)
{
    int i = blockIdx.x * 256 + threadIdx.x;          // 8-elem groups
    const float* src; f16* dst;
    if (i < 2097152)      { src = x;    dst = xh;             }
    else if (i < 2228224) { src = Wk;   dst = Wcat;           i -= 2097152; }
    else if (i < 2359296) { src = Wkg;  dst = Wcat + 1048576; i -= 2228224; }
    else                  { src = Wout; dst = Wouth;          i -= 2359296; }
    const float4* p = (const float4*)src + (size_t)i * 2;
    const float4 a = p[0], b = p[1];
    f16x8 v;
    v[0] = (f16)a.x; v[1] = (f16)a.y; v[2] = (f16)a.z; v[3] = (f16)a.w;
    v[4] = (f16)b.x; v[5] = (f16)b.y; v[6] = (f16)b.z; v[7] = (f16)b.w;
    *(f16x8*)(dst + (size_t)i * 8) = v;
}

// ---------------------------------------------------------------------------
// 256x256-tile 8-phase f16 MFMA GEMM (T3+T4 counted vmcnt, T2 swizzle via
// inverse-swizzled global source, T5 setprio). R8-proven.
// MODE 0: fp32 C0, N=1024.  MODE 1: N=2048 split: col<1024 -> f16 k (C0),
// col>=1024 -> sigmoid(+bias) f16 g (C1).
template<int MODE>
__global__ __launch_bounds__(512, 2) void gemm8(const f16* __restrict__ A,
                                                const f16* __restrict__ Bw,
                                                const float* __restrict__ bias,
                                                void* __restrict__ C0,
                                                void* __restrict__ C1)
{
    constexpr int K   = 1024;
    constexpr int NTI = MODE ? 8 : 4;   // N/256
    constexpr int NKT = 16;             // K/64
    __shared__ f16 lds[2][2][256 * 64]; // [buf][A=0/B=1], 128 KiB

    const int tid = threadIdx.x;
    const int w = tid >> 6, l = tid & 63;
    const int wm = w >> 2, wn = w & 3;
    const int lrow = l & 15;
    const int l7 = l & 7, lk = l >> 4;

    // bijective XCD swizzle (grid % 8 == 0)
    const int cpx = gridDim.x >> 3;
    const int lt  = (blockIdx.x & 7) * cpx + (blockIdx.x >> 3);
    const int bm  = (lt / NTI) * 256;
    const int bn  = (lt % NTI) * 256;

    // staging geometry: 512 threads x 2 x 16B = one 128x64 half-tile
    const int srl   = tid >> 3;                 // 0..63 row within 64-row round
    const int sg    = tid & 7;                  // LDS granule slot
    const int scolx = (sg ^ (srl & 7)) * 8;     // inverse-swizzled source col

    // swizzled ds-read granule offsets (elems) for ks=0/1
    const int g0 = ((lk) ^ l7) * 8;
    const int g1 = ((4 + lk) ^ l7) * 8;

#define STAGE(t, m, P, rowbase, h)                                                       \
    do {                                                                                 \
        const int _rf0 = (h) * 128 + srl;                                                \
        GLL((P) + (size_t)((rowbase) + _rf0) * K + (t) * 64 + scolx,                     \
            &lds[(t) & 1][m][_rf0 * 64 + sg * 8]);                                       \
        const int _rf1 = _rf0 + 64;                                                      \
        GLL((P) + (size_t)((rowbase) + _rf1) * K + (t) * 64 + scolx,                     \
            &lds[(t) & 1][m][_rf1 * 64 + sg * 8]);                                       \
    } while (0)

    f32x4 acc[8][4];
    #pragma unroll
    for (int mi = 0; mi < 8; ++mi)
        #pragma unroll
        for (int ni = 0; ni < 4; ++ni) acc[mi][ni] = (f32x4){0.f, 0.f, 0.f, 0.f};

    f16x8 bf[4][2];

#define PHASE(p, cur, STG, LOAD_B)                                                       \
    do {                                                                                 \
        const f16* _ab = &lds[cur][0][0];                                                \
        const int _ar = (wm * 128 + (2 * (p)) * 16 + lrow) * 64;                         \
        f16x8 a00 = *(const f16x8*)(_ab + _ar + g0);                                     \
        f16x8 a01 = *(const f16x8*)(_ab + _ar + g1);                                     \
        f16x8 a10 = *(const f16x8*)(_ab + _ar + 1024 + g0);                              \
        f16x8 a11 = *(const f16x8*)(_ab + _ar + 1024 + g1);                              \
        if (LOAD_B) {                                                                    \
            const f16* _bb = &lds[cur][1][0];                                            \
            _Pragma("unroll")                                                            \
            for (int ni = 0; ni < 4; ++ni) {                                             \
                const int _br = (wn * 64 + ni * 16 + lrow) * 64;                         \
                bf[ni][0] = *(const f16x8*)(_bb + _br + g0);                             \
                bf[ni][1] = *(const f16x8*)(_bb + _br + g1);                             \
            }                                                                            \
        }                                                                                \
        STG;                                                                             \
        __builtin_amdgcn_s_barrier();                                                    \
        asm volatile("s_waitcnt lgkmcnt(0)" ::: "memory");                               \
        __builtin_amdgcn_sched_barrier(0);                                               \
        __builtin_amdgcn_s_setprio(1);                                                   \
        _Pragma("unroll")                                                                \
        for (int ni = 0; ni < 4; ++ni) {                                                 \
            acc[2*(p)][ni]   = __builtin_amdgcn_mfma_f32_16x16x32_f16(a00, bf[ni][0], acc[2*(p)][ni], 0, 0, 0);   \
            acc[2*(p)][ni]   = __builtin_amdgcn_mfma_f32_16x16x32_f16(a01, bf[ni][1], acc[2*(p)][ni], 0, 0, 0);   \
            acc[2*(p)+1][ni] = __builtin_amdgcn_mfma_f32_16x16x32_f16(a10, bf[ni][0], acc[2*(p)+1][ni], 0, 0, 0); \
            acc[2*(p)+1][ni] = __builtin_amdgcn_mfma_f32_16x16x32_f16(a11, bf[ni][1], acc[2*(p)+1][ni], 0, 0, 0); \
        }                                                                                \
        __builtin_amdgcn_s_setprio(0);                                                   \
    } while (0)

    // prologue: A(0),B(0),B(1); wait A(0)+B(0) (first 8 of 12 loads)
    STAGE(0, 0, A, bm, 0);  STAGE(0, 0, A, bm, 1);
    STAGE(0, 1, Bw, bn, 0); STAGE(0, 1, Bw, bn, 1);
    STAGE(1, 1, Bw, bn, 0); STAGE(1, 1, Bw, bn, 1);
    asm volatile("s_waitcnt vmcnt(4)" ::: "memory");
    __builtin_amdgcn_s_barrier();

    for (int t = 0; t < NKT; ++t) {
        const int cur = t & 1;
        PHASE(0, cur, { if (t + 1 < NKT) STAGE(t + 1, 0, A, bm, 0); }, 1);
        __builtin_amdgcn_s_barrier();
        PHASE(1, cur, { if (t + 1 < NKT) STAGE(t + 1, 0, A, bm, 1); }, 0);
        __builtin_amdgcn_s_barrier();
        PHASE(2, cur, { if (t + 2 < NKT) STAGE(t + 2, 1, Bw, bn, 0); }, 0);
        __builtin_amdgcn_s_barrier();
        PHASE(3, cur, { if (t + 2 < NKT) STAGE(t + 2, 1, Bw, bn, 1); }, 0);
        if (t + 2 < NKT)      asm volatile("s_waitcnt vmcnt(4)" ::: "memory");
        else if (t + 1 < NKT) asm volatile("s_waitcnt vmcnt(0)" ::: "memory");
        __builtin_amdgcn_s_barrier();
    }
#undef PHASE
#undef STAGE

    // epilogue: C/D layout col = l&15, row = (l>>4)*4 + r
    const int orow = (l >> 4) * 4;
    const int ocol = l & 15;
    #pragma unroll
    for (int mi = 0; mi < 8; ++mi) {
        #pragma unroll
        for (int ni = 0; ni < 4; ++ni) {
            const int col  = bn + wn * 64 + ni * 16 + ocol;
            const int row0 = bm + wm * 128 + mi * 16 + orow;
            #pragma unroll
            for (int r = 0; r < 4; ++r) {
                float v = acc[mi][ni][r];
                if (MODE == 0) {
                    ((float*)C0)[(size_t)(row0 + r) * DIM + col] = v;
                } else {
                    if (col < DIM) {
                        ((f16*)C0)[(size_t)(row0 + r) * DIM + col] = (f16)v;     // k
                    } else {
                        v += bias[col - DIM];
                        v = 1.f / (1.f + __expf(-v));                            // g
                        ((f16*)C1)[(size_t)(row0 + r) * DIM + (col - DIM)] = (f16)v;
                    }
                }
            }
        }
    }
}

// ---------------------------------------------------------------------------
// DPP cross-lane add (VALU latency). CTRL compile-time.
template<int CTRL>
__device__ __forceinline__ float dpp_add_f(float s) {
    int t = __builtin_amdgcn_update_dpp(0, __float_as_int(s), CTRL, 0xF, 0xF, true);
    return s + __int_as_float(t);
}

__device__ __forceinline__ float sumsq4(f16x2 a, f16x2 b) {
    return __builtin_amdgcn_fdot2(a, a, __builtin_amdgcn_fdot2(b, b, 0.f, false), false);
}

#define PF 16     // prefetch depth (steps)
#define CHK 128   // output chunk length
#define WARM 128  // speculative warmup length (truncation error ~e^-50, see notes)

// Speculative chunked scan: 512 blocks = 32 wave-groups x 16 chunks.
// Wave-group w (R7-proven layout: 4 sequences, 16-lane rows, 4 dims/lane,
// packed-f16 state, 4-hop DPP butterfly) x chunk c: re-scan from h=0 starting
// at t=(c-1)*128 (c>0), discard first 128 steps (contraction makes the
// truncation error ~e^-50 << f16 rounding), write steps [c*128,(c+1)*128).
// Wall time: 256 steps instead of 2048.
__global__ __launch_bounds__(64) void scan_kernel(const f16* __restrict__ Kv,
                                                  const f16* __restrict__ Gv,
                                                  f16* __restrict__ Ov)
{
    const int w = blockIdx.x & 31;    // wave-group: batch w>>2, quad w&3
    const int c = blockIdx.x >> 5;    // chunk 0..15
    const int l = threadIdx.x;

    const int t0   = (c == 0) ? 0 : (c * CHK - WARM);
    const int warm = c * CHK - t0;    // 0 or WARM

    const size_t base = (size_t)(w >> 2) * (SEQL * DIM) + (size_t)((w & 3) * 256 + l * 4);
    size_t off = base + (size_t)t0 * DIM;

    f16x2 h01 = (f16x2){(f16)0.f, (f16)0.f};
    f16x2 h23 = (f16x2){(f16)0.f, (f16)0.f};

    f16x4 kb[PF], gb[PF];
    #pragma unroll
    for (int u = 0; u < PF; ++u) {
        kb[u] = *(const f16x4*)(Kv + off + (size_t)u * DIM);
        gb[u] = *(const f16x4*)(Gv + off + (size_t)u * DIM);
    }

    // DO_ST is a literal 0/1 -> store statically elided in warmup
    #define SCAN_STEP(kc, gc, DO_ST)                                                   \
        do {                                                                           \
            const f16x2 k01 = __builtin_shufflevector((kc), (kc), 0, 1);               \
            const f16x2 k23 = __builtin_shufflevector((kc), (kc), 2, 3);               \
            const f16x2 g01 = __builtin_shufflevector((gc), (gc), 0, 1);               \
            const f16x2 g23 = __builtin_shufflevector((gc), (gc), 2, 3);               \
            const f16x2 u01 = h01 * g01;   /* v_pk_mul_f16 */                          \
            const f16x2 u23 = h23 * g23;                                               \
            float s = sumsq4(h01, h23);                                                \
            s = dpp_add_f<0xB1>(s);   /* xor1 */                                       \
            s = dpp_add_f<0x4E>(s);   /* xor2 */                                       \
            s = dpp_add_f<0x141>(s);  /* xor4 */                                       \
            s = dpp_add_f<0x140>(s);  /* xor8 */                                       \
            const float inv = __builtin_amdgcn_rsqf(fmaf(s, 0.015625f, 1e-8f));        \
            const f16 ih = (f16)inv;                                                   \
            const f16x2 iv = (f16x2){ih, ih};                                          \
            h01 = u01 * iv + k01;          /* v_pk_fma_f16 */                          \
            h23 = u23 * iv + k23;                                                      \
            if (DO_ST) {                                                               \
                f16x4 o;                                                               \
                o[0] = h01[0]; o[1] = h01[1]; o[2] = h23[0]; o[3] = h23[1];            \
                *(f16x4*)(Ov + off) = o;                                               \
            }                                                                          \
            off += DIM;                                                                \
        } while (0)

    // warmup: warm steps (0 or WARM), consume+refill, no store
    for (int tb = 0; tb < warm; tb += PF) {
        #pragma unroll
        for (int u = 0; u < PF; ++u) {
            const f16x4 kc = kb[u], gc = gb[u];
            const size_t poff = off + (size_t)PF * DIM;
            kb[u] = *(const f16x4*)(Kv + poff);
            gb[u] = *(const f16x4*)(Gv + poff);
            SCAN_STEP(kc, gc, 0);
        }
    }
    // output with refill: CHK-PF steps (refills stay inside [t0, c*CHK+CHK))
    for (int tb = 0; tb < CHK - PF; tb += PF) {
        #pragma unroll
        for (int u = 0; u < PF; ++u) {
            const f16x4 kc = kb[u], gc = gb[u];
            const size_t poff = off + (size_t)PF * DIM;
            kb[u] = *(const f16x4*)(Kv + poff);
            gb[u] = *(const f16x4*)(Gv + poff);
            SCAN_STEP(kc, gc, 1);
        }
    }
    // tail PF steps: store, no refill
    #pragma unroll
    for (int u = 0; u < PF; ++u) {
        const f16x4 kc = kb[u], gc = gb[u];
        SCAN_STEP(kc, gc, 1);
    }
    #undef SCAN_STEP
}

// ---------------------------------------------------------------------------
extern "C" void kernel_launch(void* const* d_in, const int* in_sizes, int n_in,
                              void* d_out, int out_size, void* d_ws, size_t ws_size,
                              hipStream_t stream) {
    const float* x    = (const float*)d_in[0];
    const float* Wk   = (const float*)d_in[1];
    const float* Wkg  = (const float*)d_in[2];
    const float* bkg  = (const float*)d_in[3];
    const float* Wout = (const float*)d_in[4];
    float* out = (float*)d_out;

    // workspace (f16): xh/Kh/Gh 32MB each + Wcat 4MB + Wouth 2MB = 102MB
    f16* xh    = (f16*)d_ws;                         // [M, D]; scan output reuses it
    f16* Kh    = xh    + (size_t)MROWS * DIM;
    f16* Gh    = Kh    + (size_t)MROWS * DIM;
    f16* Wcat  = Gh    + (size_t)MROWS * DIM;        // [2048, 1024]: Wk ; Wkg
    f16* Wouth = Wcat  + (size_t)2 * DIM * DIM;

    // merged converts: one dispatch (x + Wk + Wkg + Wout), 9728 blocks
    cvt_all<<<dim3(9728), dim3(256), 0, stream>>>(x, Wk, Wkg, Wout, xh, Wcat, Wouth);

    // fused k|g GEMM: M=16384, N=2048 -> 64 x 8 = 512 blocks
    gemm8<1><<<dim3(512), dim3(512), 0, stream>>>(xh, Wcat, bkg, Kh, Gh);
    // speculative chunked scan: 32 wave-groups x 16 chunks = 512 blocks
    scan_kernel<<<dim3(512), dim3(64), 0, stream>>>(Kh, Gh, xh);
    // out = o @ Wout.T: 64 x 4 = 256 blocks
    gemm8<0><<<dim3(256), dim3(512), 0, stream>>>(xh, Wouth, nullptr, out, nullptr);
}

// Round 16
// 185.988 us; speedup vs baseline: 2.8641x; 1.0172x over previous
//
#include <hip/hip_runtime.h>
#include <hip/hip_bf16.h>
#include <math.h>

// Problem shape (fixed): B=8, L=2048, D=1024, n=16, d=64
#define BATCH 8
#define SEQL  2048
#define DIM   1024
#define MROWS (BATCH * SEQL)   // 16384

typedef _Float16 f16;
typedef _Float16 f16x8 __attribute__((ext_vector_type(8)));
typedef _Float16 f16x4 __attribute__((ext_vector_type(4)));
typedef _Float16 f16x2 __attribute__((ext_vector_type(2)));
typedef float f32x4 __attribute__((ext_vector_type(4)));

typedef const __attribute__((address_space(1))) void* gp_t;
typedef __attribute__((address_space(3))) void* lp_t;
#define GLL(src, dst) __builtin_amdgcn_global_load_lds((gp_t)(src), (lp_t)(dst), 16, 0, 0)

// ---------------------------------------------------------------------------
// merged fp32->f16 converts: x -> xh, Wk|Wkg -> Wcat, Wout -> Wouth. One dispatch.
__global__ __launch_bounds__(256) void cvt_all(const float* __restrict__ x,
                                               const float* __restrict__ Wk,
                                               const float* __restrict__ Wkg,
                                               const float* __restrict__ Wout,
                                               f16* __restrict__ xh,
                                               f16* __restrict__ Wcat,
                                               f16* __restrict__ Wouth)
{
    int i = blockIdx.x * 256 + threadIdx.x;          // 8-elem groups
    const float* src; f16* dst;
    if (i < 2097152)      { src = x;    dst = xh;             }
    else if (i < 2228224) { src = Wk;   dst = Wcat;           i -= 2097152; }
    else if (i < 2359296) { src = Wkg;  dst = Wcat + 1048576; i -= 2228224; }
    else                  { src = Wout; dst = Wouth;          i -= 2359296; }
    const float4* p = (const float4*)src + (size_t)i * 2;
    const float4 a = p[0], b = p[1];
    f16x8 v;
    v[0] = (f16)a.x; v[1] = (f16)a.y; v[2] = (f16)a.z; v[3] = (f16)a.w;
    v[4] = (f16)b.x; v[5] = (f16)b.y; v[6] = (f16)b.z; v[7] = (f16)b.w;
    *(f16x8*)(dst + (size_t)i * 8) = v;
}

// ---------------------------------------------------------------------------
// 256x256-tile 8-phase f16 MFMA GEMM, 64 KB LDS (2 blocks/CU) via in-place
// buffer rotation:
//  - A: single 32KB image, quarter-rotated. Phase p reads only A-quarter p
//    (rows wm*128+[32p,32p+32)); quarter q of tile t+1 is staged at phase q+1
//    (one full barrier after its last reader). Aq3(t) staged at t's p0.
//  - B: single 32KB image; consumed entirely into regs at p0; B(t+1) staged
//    at p1/p2.
//  - One barrier per phase: [vmcnt(K_p); s_barrier; ds_reads; stages;
//    lgkmcnt(0); sched_barrier; MFMA]. Per-wave counted vmcnt guards derived
//    from the symmetric issue queue: steady {p0:2,p1:2,p2:4,p3:6}; last tile
//    peeled with {2,2,1,0}. Never vmcnt(0) mid-loop (T4).
// MODE 0: fp32 C0, N=1024.  MODE 1: N=2048 split: col<1024 -> f16 k (C0),
// col>=1024 -> sigmoid(+bias) f16 g (C1).
template<int MODE>
__global__ __launch_bounds__(512, 2) void gemm8(const f16* __restrict__ A,
                                                const f16* __restrict__ Bw,
                                                const float* __restrict__ bias,
                                                void* __restrict__ C0,
                                                void* __restrict__ C1)
{
    constexpr int K   = 1024;
    constexpr int NTI = MODE ? 8 : 4;   // N/256
    constexpr int NKT = 16;             // K/64
    __shared__ f16 ldsA[256 * 64];      // 32 KiB, quarter-rotated
    __shared__ f16 ldsB[256 * 64];      // 32 KiB, whole-rotated after p0

    const int tid = threadIdx.x;
    const int w = tid >> 6, l = tid & 63;
    const int wm = w >> 2, wn = w & 3;
    const int lrow = l & 15;
    const int l7 = l & 7, lk = l >> 4;

    // bijective XCD swizzle (grid % 8 == 0)
    const int cpx = gridDim.x >> 3;
    const int lt  = (blockIdx.x & 7) * cpx + (blockIdx.x >> 3);
    const int bm  = (lt / NTI) * 256;
    const int bn  = (lt % NTI) * 256;

    // staging geometry
    const int srl   = tid >> 3;                 // 0..63
    const int sg    = tid & 7;                  // LDS granule slot
    const int scolx = (sg ^ (srl & 7)) * 8;     // inverse-swizzled source col
    // A-quarter p covers rows 32p+[0,32) and 128+32p+[0,32); thread stages
    // row R = 32p + aR0 (aR0 in [0,32) U [96+32,96+64) keeps R&7 == srl&7).
    const int aR0 = (srl < 32) ? srl : (96 + srl);

    // swizzled ds-read granule offsets (elems) for ks=0/1
    const int g0 = ((lk) ^ l7) * 8;
    const int g1 = ((4 + lk) ^ l7) * 8;

#define STAGE_AQ(tt, p)                                                                  \
    do {                                                                                 \
        const int _R = 32 * (p) + aR0;                                                   \
        GLL(A + (size_t)(bm + _R) * K + (tt) * 64 + scolx, ldsA + _R * 64 + sg * 8);     \
    } while (0)

#define STAGE_BH(tt, h)                                                                  \
    do {                                                                                 \
        const int _r0 = (h) * 128 + srl;                                                 \
        GLL(Bw + (size_t)(bn + _r0) * K + (tt) * 64 + scolx, ldsB + _r0 * 64 + sg * 8);  \
        const int _r1 = _r0 + 64;                                                        \
        GLL(Bw + (size_t)(bn + _r1) * K + (tt) * 64 + scolx, ldsB + _r1 * 64 + sg * 8);  \
    } while (0)

    f32x4 acc[8][4];
    #pragma unroll
    for (int mi = 0; mi < 8; ++mi)
        #pragma unroll
        for (int ni = 0; ni < 4; ++ni) acc[mi][ni] = (f32x4){0.f, 0.f, 0.f, 0.f};

    f16x8 bf[4][2];

#define PHASE(p, VK, STG)                                                                \
    do {                                                                                 \
        asm volatile("s_waitcnt vmcnt(" #VK ")" ::: "memory");                           \
        __builtin_amdgcn_s_barrier();                                                    \
        const int _ar = (wm * 128 + 32 * (p) + lrow) * 64;                               \
        f16x8 a00 = *(const f16x8*)(ldsA + _ar + g0);                                    \
        f16x8 a01 = *(const f16x8*)(ldsA + _ar + g1);                                    \
        f16x8 a10 = *(const f16x8*)(ldsA + _ar + 1024 + g0);                             \
        f16x8 a11 = *(const f16x8*)(ldsA + _ar + 1024 + g1);                             \
        if ((p) == 0) {                                                                  \
            _Pragma("unroll")                                                            \
            for (int ni = 0; ni < 4; ++ni) {                                             \
                const int _br = (wn * 64 + ni * 16 + lrow) * 64;                         \
                bf[ni][0] = *(const f16x8*)(ldsB + _br + g0);                            \
                bf[ni][1] = *(const f16x8*)(ldsB + _br + g1);                            \
            }                                                                            \
        }                                                                                \
        STG;                                                                             \
        asm volatile("s_waitcnt lgkmcnt(0)" ::: "memory");                               \
        __builtin_amdgcn_sched_barrier(0);                                               \
        __builtin_amdgcn_s_setprio(1);                                                   \
        _Pragma("unroll")                                                                \
        for (int ni = 0; ni < 4; ++ni) {                                                 \
            acc[2*(p)][ni]   = __builtin_amdgcn_mfma_f32_16x16x32_f16(a00, bf[ni][0], acc[2*(p)][ni], 0, 0, 0);   \
            acc[2*(p)][ni]   = __builtin_amdgcn_mfma_f32_16x16x32_f16(a01, bf[ni][1], acc[2*(p)][ni], 0, 0, 0);   \
            acc[2*(p)+1][ni] = __builtin_amdgcn_mfma_f32_16x16x32_f16(a10, bf[ni][0], acc[2*(p)+1][ni], 0, 0, 0); \
            acc[2*(p)+1][ni] = __builtin_amdgcn_mfma_f32_16x16x32_f16(a11, bf[ni][1], acc[2*(p)+1][ni], 0, 0, 0); \
        }                                                                                \
        __builtin_amdgcn_s_setprio(0);                                                   \
    } while (0)

    // prologue, steady-state issue order: [Bh0 x2, Aq0, Bh1 x2, Aq1, Aq2] of t=0
    STAGE_BH(0, 0); STAGE_AQ(0, 0);
    STAGE_BH(0, 1); STAGE_AQ(0, 1);
    STAGE_AQ(0, 2);

    for (int t = 0; t < NKT - 1; ++t) {
        PHASE(0, 2, { STAGE_AQ(t, 3); });
        PHASE(1, 2, { STAGE_BH(t + 1, 0); STAGE_AQ(t + 1, 0); });
        PHASE(2, 4, { STAGE_BH(t + 1, 1); STAGE_AQ(t + 1, 1); });
        PHASE(3, 6, { STAGE_AQ(t + 1, 2); });
    }
    // last tile: no next-tile stages; shallow queue -> tighter guards
    PHASE(0, 2, { STAGE_AQ(NKT - 1, 3); });
    PHASE(1, 2, {});
    PHASE(2, 1, {});
    PHASE(3, 0, {});
#undef PHASE
#undef STAGE_AQ
#undef STAGE_BH

    // epilogue: C/D layout col = l&15, row = (l>>4)*4 + r
    const int orow = (l >> 4) * 4;
    const int ocol = l & 15;
    #pragma unroll
    for (int mi = 0; mi < 8; ++mi) {
        #pragma unroll
        for (int ni = 0; ni < 4; ++ni) {
            const int col  = bn + wn * 64 + ni * 16 + ocol;
            const int row0 = bm + wm * 128 + mi * 16 + orow;
            #pragma unroll
            for (int r = 0; r < 4; ++r) {
                float v = acc[mi][ni][r];
                if (MODE == 0) {
                    ((float*)C0)[(size_t)(row0 + r) * DIM + col] = v;
                } else {
                    if (col < DIM) {
                        ((f16*)C0)[(size_t)(row0 + r) * DIM + col] = (f16)v;     // k
                    } else {
                        v += bias[col - DIM];
                        v = 1.f / (1.f + __expf(-v));                            // g
                        ((f16*)C1)[(size_t)(row0 + r) * DIM + (col - DIM)] = (f16)v;
                    }
                }
            }
        }
    }
}

// ---------------------------------------------------------------------------
// DPP cross-lane add (VALU latency). CTRL compile-time.
template<int CTRL>
__device__ __forceinline__ float dpp_add_f(float s) {
    int t = __builtin_amdgcn_update_dpp(0, __float_as_int(s), CTRL, 0xF, 0xF, true);
    return s + __int_as_float(t);
}

__device__ __forceinline__ float sumsq4(f16x2 a, f16x2 b) {
    return __builtin_amdgcn_fdot2(a, a, __builtin_amdgcn_fdot2(b, b, 0.f, false), false);
}

#define PF 16     // prefetch depth (steps)
#define CHK 128   // output chunk length
#define WARM 128  // speculative warmup length (truncation error ~e^-50)

// Speculative chunked scan (R15-proven): 512 blocks = 32 wave-groups x 16
// chunks; chunk c re-scans from h=0 at t=(c-1)*128, discards 128 warmup
// steps, writes [c*128,(c+1)*128). Wall: 256 steps instead of 2048.
__global__ __launch_bounds__(64) void scan_kernel(const f16* __restrict__ Kv,
                                                  const f16* __restrict__ Gv,
                                                  f16* __restrict__ Ov)
{
    const int w = blockIdx.x & 31;    // wave-group: batch w>>2, quad w&3
    const int c = blockIdx.x >> 5;    // chunk 0..15
    const int l = threadIdx.x;

    const int t0   = (c == 0) ? 0 : (c * CHK - WARM);
    const int warm = c * CHK - t0;    // 0 or WARM

    const size_t base = (size_t)(w >> 2) * (SEQL * DIM) + (size_t)((w & 3) * 256 + l * 4);
    size_t off = base + (size_t)t0 * DIM;

    f16x2 h01 = (f16x2){(f16)0.f, (f16)0.f};
    f16x2 h23 = (f16x2){(f16)0.f, (f16)0.f};

    f16x4 kb[PF], gb[PF];
    #pragma unroll
    for (int u = 0; u < PF; ++u) {
        kb[u] = *(const f16x4*)(Kv + off + (size_t)u * DIM);
        gb[u] = *(const f16x4*)(Gv + off + (size_t)u * DIM);
    }

    #define SCAN_STEP(kc, gc, DO_ST)                                                   \
        do {                                                                           \
            const f16x2 k01 = __builtin_shufflevector((kc), (kc), 0, 1);               \
            const f16x2 k23 = __builtin_shufflevector((kc), (kc), 2, 3);               \
            const f16x2 g01 = __builtin_shufflevector((gc), (gc), 0, 1);               \
            const f16x2 g23 = __builtin_shufflevector((gc), (gc), 2, 3);               \
            const f16x2 u01 = h01 * g01;                                               \
            const f16x2 u23 = h23 * g23;                                               \
            float s = sumsq4(h01, h23);                                                \
            s = dpp_add_f<0xB1>(s);                                                    \
            s = dpp_add_f<0x4E>(s);                                                    \
            s = dpp_add_f<0x141>(s);                                                   \
            s = dpp_add_f<0x140>(s);                                                   \
            const float inv = __builtin_amdgcn_rsqf(fmaf(s, 0.015625f, 1e-8f));        \
            const f16 ih = (f16)inv;                                                   \
            const f16x2 iv = (f16x2){ih, ih};                                          \
            h01 = u01 * iv + k01;                                                      \
            h23 = u23 * iv + k23;                                                      \
            if (DO_ST) {                                                               \
                f16x4 o;                                                               \
                o[0] = h01[0]; o[1] = h01[1]; o[2] = h23[0]; o[3] = h23[1];            \
                *(f16x4*)(Ov + off) = o;                                               \
            }                                                                          \
            off += DIM;                                                                \
        } while (0)

    for (int tb = 0; tb < warm; tb += PF) {
        #pragma unroll
        for (int u = 0; u < PF; ++u) {
            const f16x4 kc = kb[u], gc = gb[u];
            const size_t poff = off + (size_t)PF * DIM;
            kb[u] = *(const f16x4*)(Kv + poff);
            gb[u] = *(const f16x4*)(Gv + poff);
            SCAN_STEP(kc, gc, 0);
        }
    }
    for (int tb = 0; tb < CHK - PF; tb += PF) {
        #pragma unroll
        for (int u = 0; u < PF; ++u) {
            const f16x4 kc = kb[u], gc = gb[u];
            const size_t poff = off + (size_t)PF * DIM;
            kb[u] = *(const f16x4*)(Kv + poff);
            gb[u] = *(const f16x4*)(Gv + poff);
            SCAN_STEP(kc, gc, 1);
        }
    }
    #pragma unroll
    for (int u = 0; u < PF; ++u) {
        const f16x4 kc = kb[u], gc = gb[u];
        SCAN_STEP(kc, gc, 1);
    }
    #undef SCAN_STEP
}

// ---------------------------------------------------------------------------
extern "C" void kernel_launch(void* const* d_in, const int* in_sizes, int n_in,
                              void* d_out, int out_size, void* d_ws, size_t ws_size,
                              hipStream_t stream) {
    const float* x    = (const float*)d_in[0];
    const float* Wk   = (const float*)d_in[1];
    const float* Wkg  = (const float*)d_in[2];
    const float* bkg  = (const float*)d_in[3];
    const float* Wout = (const float*)d_in[4];
    float* out = (float*)d_out;

    // workspace (f16): xh/Kh/Gh 32MB each + Wcat 4MB + Wouth 2MB = 102MB
    f16* xh    = (f16*)d_ws;                         // [M, D]; scan output reuses it
    f16* Kh    = xh    + (size_t)MROWS * DIM;
    f16* Gh    = Kh    + (size_t)MROWS * DIM;
    f16* Wcat  = Gh    + (size_t)MROWS * DIM;        // [2048, 1024]: Wk ; Wkg
    f16* Wouth = Wcat  + (size_t)2 * DIM * DIM;

    // merged converts: one dispatch (x + Wk + Wkg + Wout), 9728 blocks
    cvt_all<<<dim3(9728), dim3(256), 0, stream>>>(x, Wk, Wkg, Wout, xh, Wcat, Wouth);

    // fused k|g GEMM: M=16384, N=2048 -> 64 x 8 = 512 blocks (2/CU resident)
    gemm8<1><<<dim3(512), dim3(512), 0, stream>>>(xh, Wcat, bkg, Kh, Gh);
    // speculative chunked scan: 32 wave-groups x 16 chunks = 512 blocks
    scan_kernel<<<dim3(512), dim3(64), 0, stream>>>(Kh, Gh, xh);
    // out = o @ Wout.T: 64 x 4 = 256 blocks
    gemm8<0><<<dim3(256), dim3(512), 0, stream>>>(xh, Wouth, nullptr, out, nullptr);
}